// Round 4
// baseline (261.128 us; speedup 1.0000x reference)
//
#include <hip/hip_runtime.h>
#include <math.h>

// GEBLNet via Gram-matrix reduction (R4).
// Layer 2 is only consumed through its trace:
//   T[u] = sum_{v,w} w2[u,v,w] * tr(We2[v] @ We2[w]) = sum_{v,w} w2[u,v,w]*G[v,w]
// G has only 169 unique values [78 S | 78 Hm | 12 tr | 1 const]; all w2
// coefficients fold per-launch into CTt[169][12] float4 (setup kernel).
// Layer 1 computed exactly (full H needed): thread=(p,u,k) owns column k of
// H[u]; w1 staged in LDS (padded rows), We1 k-column preloaded to regs.
// __launch_bounds__(256,4): VGPR<=128 -> 4 blocks/CU (LDS 36KB -> 144KB/CU).

#define NPTS 8192
#define NP 7
#define THRESH 0.001f

__global__ void geblnet_setup(const float* __restrict__ w2,
                              float4* __restrict__ CTt) {
    int j = blockIdx.x * blockDim.x + threadIdx.x;
    if (j >= 12 * 169) return;
    int u = j / 169, it = j % 169;
    const float* W = w2 + u * 25 * 25 * 2;
#define WR(v, w) W[((v) * 25 + (w)) * 2]
#define WI(v, w) W[((v) * 25 + (w)) * 2 + 1]
    float c0, c1, c2, c3;
    if (it < 78) {                       // S pairs, a<=b
        int q = it, a = 0;
        while (q >= 12 - a) { q -= 12 - a; ++a; }
        int b = a + q;
        float ar = WR(a, b) + (a != b ? WR(b, a) : 0.f);
        float ai = WI(a, b) + (a != b ? WI(b, a) : 0.f);
        float br = WR(12 + a, 12 + b) + (a != b ? WR(12 + b, 12 + a) : 0.f);
        float bi = WI(12 + a, 12 + b) + (a != b ? WI(12 + b, 12 + a) : 0.f);
        c0 = ar + br; c1 = bi - ai; c2 = ai + bi; c3 = ar - br;
    } else if (it < 156) {               // Hm pairs, a<=b
        int q = it - 78, a = 0;
        while (q >= 12 - a) { q -= 12 - a; ++a; }
        int b = a + q;
        if (a != b) {
            float gr = WR(a, 12 + b) + WR(12 + b, a);
            float gi = WI(a, 12 + b) + WI(12 + b, a);
            float dr = WR(b, 12 + a) + WR(12 + a, b);
            float di = WI(b, 12 + a) + WI(12 + a, b);
            c0 = gr + dr; c1 = di - gi; c2 = gi + di; c3 = gr - dr;
        } else {
            float er = WR(a, 12 + a) + WR(12 + a, a);
            float ei = WI(a, 12 + a) + WI(12 + a, a);
            c0 = er; c1 = 0.f; c2 = ei; c3 = 0.f;
        }
    } else if (it < 168) {               // trace terms
        int a = it - 156;
        float fr = WR(a, 24) + WR(24, a), fi = WI(a, 24) + WI(24, a);
        float pr = WR(12 + a, 24) + WR(24, 12 + a);
        float pi = WI(12 + a, 24) + WI(24, 12 + a);
        c0 = fr + pr; c1 = pi - fi; c2 = fi + pi; c3 = fr - pr;
    } else {                             // unit-unit
        c0 = 3.f * WR(24, 24); c1 = 0.f; c2 = 3.f * WI(24, 24); c3 = 0.f;
    }
    CTt[it * 12 + u] = make_float4(c0, c1, c2, c3);
#undef WR
#undef WI
}

__global__ __launch_bounds__(256, 4) void geblnet_main(
    const float2* __restrict__ x2,      // (8192, 10, 9) complex
    const float2* __restrict__ w1g,     // (12,13,13) complex
    const float* __restrict__ dw,       // (24,)
    const float* __restrict__ db,       // (1,)
    const float4* __restrict__ CTt,     // (169,12)
    float* __restrict__ out)            // (8192,)
{
    // w1 staged with w-dim padded 13->14 so each (u,v) row is 16B-aligned.
    __shared__ __align__(16) float2 w1s[12 * 13 * 14];   // 17472 B
    // Overlay: phases 1-2 = We1 (channel stride 10, p stride 130);
    //          phases 4-5 = GV  (p stride 169). Disjoint lifetimes.
    __shared__ __align__(16) float2 WeGV[NP * 169];      // 9464 B
    __shared__ float2 Hs[NP][108];                       // 6048 B
    __shared__ float2 Tpar[NP][36];                      // 2016 B
    __shared__ float2 tr1[NP][12];
    __shared__ float  sc1[NP][12];

    const int t = threadIdx.x;
    const int pbase = blockIdx.x * NP;

    // ---- phase 0: stage w1 into LDS (re-laid, padded)
    for (int j = t; j < 12 * 13 * 13; j += 256) {
        int row = j / 13, w = j - row * 13;
        w1s[row * 14 + w] = w1g[j];
    }
    // ---- phase 1: build We1
    for (int j = t; j < NP * 117; j += 256) {
        int p = j / 117, rr = j - p * 117;
        if (pbase + p < NPTS) {
            int v = rr / 9, ik = rr - v * 9;
            int i = ik / 3, jj = ik - i * 3;
            const float2* xp = x2 + (size_t)(pbase + p) * 90;
            float2 val;
            if (v < 6)       val = xp[(4 + v) * 9 + ik];
            else if (v < 12) { float2 s = xp[(v - 2) * 9 + jj * 3 + i]; val = make_float2(s.x, -s.y); }
            else             val = make_float2((i == jj) ? 1.f : 0.f, 0.f);
            WeGV[p * 130 + v * 10 + ik] = val;
        }
    }
    __syncthreads();

    // ---- phase 2: layer 1, thread=(p,u,k), 252 active, LDS-only inner loop
    if (t < NP * 36) {
        int p = t / 36, r = t - p * 36, u = r / 3, k = r - u * 3;
        if (pbase + p < NPTS) {
            const float2* Wp = &WeGV[p * 130];
            float2 wc[13][3];
            #pragma unroll
            for (int w = 0; w < 13; ++w)
                #pragma unroll
                for (int jj = 0; jj < 3; ++jj)
                    wc[w][jj] = Wp[w * 10 + jj * 3 + k];
            float2 h0 = make_float2(0.f, 0.f), h1 = h0, h2 = h0;
            const float2* wrow = &w1s[u * 182];
            for (int v = 0; v < 13; ++v) {
                const float2* cv = wrow + v * 14;
                float b0r = 0.f, b0i = 0.f, b1r = 0.f, b1i = 0.f, b2r = 0.f, b2i = 0.f;
                #pragma unroll
                for (int w = 0; w < 13; ++w) {
                    float2 c = cv[w];
                    b0r += c.x * wc[w][0].x - c.y * wc[w][0].y;
                    b0i += c.x * wc[w][0].y + c.y * wc[w][0].x;
                    b1r += c.x * wc[w][1].x - c.y * wc[w][1].y;
                    b1i += c.x * wc[w][1].y + c.y * wc[w][1].x;
                    b2r += c.x * wc[w][2].x - c.y * wc[w][2].y;
                    b2i += c.x * wc[w][2].y + c.y * wc[w][2].x;
                }
                const float2* row = Wp + v * 10;
                #pragma unroll
                for (int i = 0; i < 3; ++i) {
                    float2 a0 = row[i * 3 + 0], a1 = row[i * 3 + 1], a2 = row[i * 3 + 2];
                    float hr = a0.x * b0r - a0.y * b0i
                             + a1.x * b1r - a1.y * b1i
                             + a2.x * b2r - a2.y * b2i;
                    float hi = a0.x * b0i + a0.y * b0r
                             + a1.x * b1i + a1.y * b1r
                             + a2.x * b2i + a2.y * b2r;
                    if (i == 0)      { h0.x += hr; h0.y += hi; }
                    else if (i == 1) { h1.x += hr; h1.y += hi; }
                    else             { h2.x += hr; h2.y += hi; }
                }
            }
            Hs[p][u * 9 + 0 + k] = h0;
            Hs[p][u * 9 + 3 + k] = h1;
            Hs[p][u * 9 + 6 + k] = h2;
        }
    }
    __syncthreads();

    // ---- phase 3: traces + gerelu + trnorm scales
    if (t < NP && pbase + t < NPTS) {
        int p = t;
        float m = 0.f; float g[12]; float2 tl[12];
        #pragma unroll
        for (int u = 0; u < 12; ++u) {
            float2 a = Hs[p][u * 9 + 0], b = Hs[p][u * 9 + 4], c = Hs[p][u * 9 + 8];
            float2 tt = make_float2(a.x + b.x + c.x, a.y + b.y + c.y);
            tl[u] = tt;
            float gg = tt.x > 0.f ? tt.x : 0.f;
            g[u] = gg;
            m += gg * sqrtf(tt.x * tt.x + tt.y * tt.y);
        }
        float inv = 1.f / fmaxf(m * (1.f / 12.f), THRESH);
        #pragma unroll
        for (int u = 0; u < 12; ++u) { sc1[p][u] = g[u] * inv; tr1[p][u] = tl[u]; }
    }
    __syncthreads();

    // ---- phase 4: Gram values -> GV (overlays We1; We1 dead since phase 2)
    for (int j = t; j < NP * 169; j += 256) {
        int p = j / 169, it = j - p * 169;
        if (pbase + p >= NPTS) continue;
        float2 val;
        if (it < 156) {
            int q = it < 78 ? it : it - 78;
            float fs = sqrtf(625.0f - 8.0f * (float)q);   // exact at bucket edges
            int a = (int)((25.0f - fs) * 0.5f);
            int b = q - (a * (25 - a)) / 2 + a;
            const float2* Ha = &Hs[p][a * 9];
            const float2* Hb = &Hs[p][b * 9];
            float s = sc1[p][a] * sc1[p][b];
            float vr = 0.f, vi = 0.f;
            if (it < 78) {                    // S = tr(Aa Ab)
                #pragma unroll
                for (int i = 0; i < 3; ++i)
                    #pragma unroll
                    for (int jj = 0; jj < 3; ++jj) {
                        float2 A = Ha[i * 3 + jj], B = Hb[jj * 3 + i];
                        vr += A.x * B.x - A.y * B.y;
                        vi += A.x * B.y + A.y * B.x;
                    }
            } else {                          // Hm = tr(Aa Ab^H)
                #pragma unroll
                for (int e = 0; e < 9; ++e) {
                    float2 A = Ha[e], B = Hb[e];
                    vr += A.x * B.x + A.y * B.y;
                    vi += A.y * B.x - A.x * B.y;
                }
            }
            val = make_float2(s * vr, s * vi);
        } else if (it < 168) {
            int a = it - 156;
            float s = sc1[p][a]; float2 tt = tr1[p][a];
            val = make_float2(s * tt.x, s * tt.y);
        } else {
            val = make_float2(1.f, 0.f);
        }
        WeGV[p * 169 + it] = val;
    }
    __syncthreads();

    // ---- phase 5: coefficient contraction, thread=(q,p,u); CTt coalesced in u
    if (t < 252) {
        int q = t / 84, r = t - q * 84, p = r / 12, u = r - p * 12;
        if (pbase + p < NPTS) {
            int i0 = q * 57, i1 = (q == 2) ? 169 : i0 + 57;
            float tre = 0.f, tim = 0.f;
            for (int it = i0; it < i1; ++it) {
                float4 c = CTt[it * 12 + u];
                float2 gv = WeGV[p * 169 + it];
                tre += c.x * gv.x + c.y * gv.y;
                tim += c.z * gv.x + c.w * gv.y;
            }
            Tpar[p][u * 3 + q] = make_float2(tre, tim);
        }
    }
    __syncthreads();

    // ---- phase 6: layer-2 gerelu + trnorm + dense head
    if (t < NP && pbase + t < NPTS) {
        int p = t;
        float m = 0.f; float2 T[12]; float gg[12];
        #pragma unroll
        for (int u = 0; u < 12; ++u) {
            float2 A = Tpar[p][u * 3], B = Tpar[p][u * 3 + 1], C = Tpar[p][u * 3 + 2];
            float2 tt = make_float2(A.x + B.x + C.x, A.y + B.y + C.y);
            T[u] = tt;
            float g = tt.x > 0.f ? tt.x : 0.f;
            gg[u] = g;
            m += g * sqrtf(tt.x * tt.x + tt.y * tt.y);
        }
        float inv = 1.f / fmaxf(m * (1.f / 12.f), THRESH);
        float acc = db[0];
        #pragma unroll
        for (int u = 0; u < 12; ++u) {
            float s = gg[u] * inv * (1.f / 3.f);
            acc += s * (T[u].x * dw[2 * u] + T[u].y * dw[2 * u + 1]);
        }
        out[pbase + p] = acc;
    }
}

extern "C" void kernel_launch(void* const* d_in, const int* in_sizes, int n_in,
                              void* d_out, int out_size, void* d_ws, size_t ws_size,
                              hipStream_t stream) {
    const float* x  = (const float*)d_in[0];
    const float* w1 = (const float*)d_in[1];
    const float* w2 = (const float*)d_in[2];
    const float* dw = (const float*)d_in[3];
    const float* db = (const float*)d_in[4];
    float* outp = (float*)d_out;
    float4* CTt = (float4*)d_ws;          // 12*169*16 B = 32448 B

    geblnet_setup<<<(12 * 169 + 255) / 256, 256, 0, stream>>>(w2, CTt);

    const int nblocks = (NPTS + NP - 1) / NP;   // 1171
    geblnet_main<<<nblocks, 256, 0, stream>>>(
        (const float2*)x, (const float2*)w1, dw, db, CTt, outp);
}

// Round 5
// 189.912 us; speedup vs baseline: 1.3750x; 1.3750x over previous
//
#include <hip/hip_runtime.h>
#include <math.h>

// GEBLNet via Gram-matrix reduction (R5 = R4 minus forced launch_bounds).
// Layer 2 is only consumed through its trace:
//   T[u] = sum_{v,w} w2[u,v,w] * tr(We2[v] @ We2[w]) = sum_{v,w} w2[u,v,w]*G[v,w]
// G has only 169 unique values [78 S | 78 Hm | 12 tr | 1 const]; all w2
// coefficients fold per-launch into CTt[169][12] float4 (setup kernel).
// Layer 1 computed exactly (full H needed): thread=(p,u,k) owns column k of
// H[u]; w1 staged in LDS (padded rows), We1 k-column preloaded to regs.
// NOTE R4 lesson: __launch_bounds__(256,4) forced VGPR 140->64 and spilled
// wc[] to scratch (FETCH 373 MB, 27% HBM peak). Natural allocation (~140
// VGPR, 3 blocks/CU) is strictly better than spilling for 4 blocks/CU.

#define NPTS 8192
#define NP 7
#define THRESH 0.001f

__global__ void geblnet_setup(const float* __restrict__ w2,
                              float4* __restrict__ CTt) {
    int j = blockIdx.x * blockDim.x + threadIdx.x;
    if (j >= 12 * 169) return;
    int u = j / 169, it = j % 169;
    const float* W = w2 + u * 25 * 25 * 2;
#define WR(v, w) W[((v) * 25 + (w)) * 2]
#define WI(v, w) W[((v) * 25 + (w)) * 2 + 1]
    float c0, c1, c2, c3;
    if (it < 78) {                       // S pairs, a<=b
        int q = it, a = 0;
        while (q >= 12 - a) { q -= 12 - a; ++a; }
        int b = a + q;
        float ar = WR(a, b) + (a != b ? WR(b, a) : 0.f);
        float ai = WI(a, b) + (a != b ? WI(b, a) : 0.f);
        float br = WR(12 + a, 12 + b) + (a != b ? WR(12 + b, 12 + a) : 0.f);
        float bi = WI(12 + a, 12 + b) + (a != b ? WI(12 + b, 12 + a) : 0.f);
        c0 = ar + br; c1 = bi - ai; c2 = ai + bi; c3 = ar - br;
    } else if (it < 156) {               // Hm pairs, a<=b
        int q = it - 78, a = 0;
        while (q >= 12 - a) { q -= 12 - a; ++a; }
        int b = a + q;
        if (a != b) {
            float gr = WR(a, 12 + b) + WR(12 + b, a);
            float gi = WI(a, 12 + b) + WI(12 + b, a);
            float dr = WR(b, 12 + a) + WR(12 + a, b);
            float di = WI(b, 12 + a) + WI(12 + a, b);
            c0 = gr + dr; c1 = di - gi; c2 = gi + di; c3 = gr - dr;
        } else {
            float er = WR(a, 12 + a) + WR(12 + a, a);
            float ei = WI(a, 12 + a) + WI(12 + a, a);
            c0 = er; c1 = 0.f; c2 = ei; c3 = 0.f;
        }
    } else if (it < 168) {               // trace terms
        int a = it - 156;
        float fr = WR(a, 24) + WR(24, a), fi = WI(a, 24) + WI(24, a);
        float pr = WR(12 + a, 24) + WR(24, 12 + a);
        float pi = WI(12 + a, 24) + WI(24, 12 + a);
        c0 = fr + pr; c1 = pi - fi; c2 = fi + pi; c3 = fr - pr;
    } else {                             // unit-unit
        c0 = 3.f * WR(24, 24); c1 = 0.f; c2 = 3.f * WI(24, 24); c3 = 0.f;
    }
    CTt[it * 12 + u] = make_float4(c0, c1, c2, c3);
#undef WR
#undef WI
}

__global__ __launch_bounds__(256) void geblnet_main(
    const float2* __restrict__ x2,      // (8192, 10, 9) complex
    const float2* __restrict__ w1g,     // (12,13,13) complex
    const float* __restrict__ dw,       // (24,)
    const float* __restrict__ db,       // (1,)
    const float4* __restrict__ CTt,     // (169,12)
    float* __restrict__ out)            // (8192,)
{
    // w1 staged with w-dim padded 13->14 so each (u,v) row is 16B-aligned.
    __shared__ __align__(16) float2 w1s[12 * 13 * 14];   // 17472 B
    // Overlay: phases 1-2 = We1 (channel stride 10, p stride 130);
    //          phases 4-5 = GV  (p stride 169). Disjoint lifetimes.
    __shared__ __align__(16) float2 WeGV[NP * 169];      // 9464 B
    __shared__ float2 Hs[NP][108];                       // 6048 B
    __shared__ float2 Tpar[NP][36];                      // 2016 B
    __shared__ float2 tr1[NP][12];
    __shared__ float  sc1[NP][12];

    const int t = threadIdx.x;
    const int pbase = blockIdx.x * NP;

    // ---- phase 0: stage w1 into LDS (re-laid, padded)
    for (int j = t; j < 12 * 13 * 13; j += 256) {
        int row = j / 13, w = j - row * 13;
        w1s[row * 14 + w] = w1g[j];
    }
    // ---- phase 1: build We1
    for (int j = t; j < NP * 117; j += 256) {
        int p = j / 117, rr = j - p * 117;
        if (pbase + p < NPTS) {
            int v = rr / 9, ik = rr - v * 9;
            int i = ik / 3, jj = ik - i * 3;
            const float2* xp = x2 + (size_t)(pbase + p) * 90;
            float2 val;
            if (v < 6)       val = xp[(4 + v) * 9 + ik];
            else if (v < 12) { float2 s = xp[(v - 2) * 9 + jj * 3 + i]; val = make_float2(s.x, -s.y); }
            else             val = make_float2((i == jj) ? 1.f : 0.f, 0.f);
            WeGV[p * 130 + v * 10 + ik] = val;
        }
    }
    __syncthreads();

    // ---- phase 2: layer 1, thread=(p,u,k), 252 active, LDS-only inner loop
    if (t < NP * 36) {
        int p = t / 36, r = t - p * 36, u = r / 3, k = r - u * 3;
        if (pbase + p < NPTS) {
            const float2* Wp = &WeGV[p * 130];
            float2 wc[13][3];
            #pragma unroll
            for (int w = 0; w < 13; ++w)
                #pragma unroll
                for (int jj = 0; jj < 3; ++jj)
                    wc[w][jj] = Wp[w * 10 + jj * 3 + k];
            float2 h0 = make_float2(0.f, 0.f), h1 = h0, h2 = h0;
            const float2* wrow = &w1s[u * 182];
            for (int v = 0; v < 13; ++v) {
                const float2* cv = wrow + v * 14;
                float b0r = 0.f, b0i = 0.f, b1r = 0.f, b1i = 0.f, b2r = 0.f, b2i = 0.f;
                #pragma unroll
                for (int w = 0; w < 13; ++w) {
                    float2 c = cv[w];
                    b0r += c.x * wc[w][0].x - c.y * wc[w][0].y;
                    b0i += c.x * wc[w][0].y + c.y * wc[w][0].x;
                    b1r += c.x * wc[w][1].x - c.y * wc[w][1].y;
                    b1i += c.x * wc[w][1].y + c.y * wc[w][1].x;
                    b2r += c.x * wc[w][2].x - c.y * wc[w][2].y;
                    b2i += c.x * wc[w][2].y + c.y * wc[w][2].x;
                }
                const float2* row = Wp + v * 10;
                #pragma unroll
                for (int i = 0; i < 3; ++i) {
                    float2 a0 = row[i * 3 + 0], a1 = row[i * 3 + 1], a2 = row[i * 3 + 2];
                    float hr = a0.x * b0r - a0.y * b0i
                             + a1.x * b1r - a1.y * b1i
                             + a2.x * b2r - a2.y * b2i;
                    float hi = a0.x * b0i + a0.y * b0r
                             + a1.x * b1i + a1.y * b1r
                             + a2.x * b2i + a2.y * b2r;
                    if (i == 0)      { h0.x += hr; h0.y += hi; }
                    else if (i == 1) { h1.x += hr; h1.y += hi; }
                    else             { h2.x += hr; h2.y += hi; }
                }
            }
            Hs[p][u * 9 + 0 + k] = h0;
            Hs[p][u * 9 + 3 + k] = h1;
            Hs[p][u * 9 + 6 + k] = h2;
        }
    }
    __syncthreads();

    // ---- phase 3: traces + gerelu + trnorm scales
    if (t < NP && pbase + t < NPTS) {
        int p = t;
        float m = 0.f; float g[12]; float2 tl[12];
        #pragma unroll
        for (int u = 0; u < 12; ++u) {
            float2 a = Hs[p][u * 9 + 0], b = Hs[p][u * 9 + 4], c = Hs[p][u * 9 + 8];
            float2 tt = make_float2(a.x + b.x + c.x, a.y + b.y + c.y);
            tl[u] = tt;
            float gg = tt.x > 0.f ? tt.x : 0.f;
            g[u] = gg;
            m += gg * sqrtf(tt.x * tt.x + tt.y * tt.y);
        }
        float inv = 1.f / fmaxf(m * (1.f / 12.f), THRESH);
        #pragma unroll
        for (int u = 0; u < 12; ++u) { sc1[p][u] = g[u] * inv; tr1[p][u] = tl[u]; }
    }
    __syncthreads();

    // ---- phase 4: Gram values -> GV (overlays We1; We1 dead since phase 2)
    for (int j = t; j < NP * 169; j += 256) {
        int p = j / 169, it = j - p * 169;
        if (pbase + p >= NPTS) continue;
        float2 val;
        if (it < 156) {
            int q = it < 78 ? it : it - 78;
            float fs = sqrtf(625.0f - 8.0f * (float)q);   // exact at bucket edges
            int a = (int)((25.0f - fs) * 0.5f);
            int b = q - (a * (25 - a)) / 2 + a;
            const float2* Ha = &Hs[p][a * 9];
            const float2* Hb = &Hs[p][b * 9];
            float s = sc1[p][a] * sc1[p][b];
            float vr = 0.f, vi = 0.f;
            if (it < 78) {                    // S = tr(Aa Ab)
                #pragma unroll
                for (int i = 0; i < 3; ++i)
                    #pragma unroll
                    for (int jj = 0; jj < 3; ++jj) {
                        float2 A = Ha[i * 3 + jj], B = Hb[jj * 3 + i];
                        vr += A.x * B.x - A.y * B.y;
                        vi += A.x * B.y + A.y * B.x;
                    }
            } else {                          // Hm = tr(Aa Ab^H)
                #pragma unroll
                for (int e = 0; e < 9; ++e) {
                    float2 A = Ha[e], B = Hb[e];
                    vr += A.x * B.x + A.y * B.y;
                    vi += A.y * B.x - A.x * B.y;
                }
            }
            val = make_float2(s * vr, s * vi);
        } else if (it < 168) {
            int a = it - 156;
            float s = sc1[p][a]; float2 tt = tr1[p][a];
            val = make_float2(s * tt.x, s * tt.y);
        } else {
            val = make_float2(1.f, 0.f);
        }
        WeGV[p * 169 + it] = val;
    }
    __syncthreads();

    // ---- phase 5: coefficient contraction, thread=(q,p,u); CTt coalesced in u
    if (t < 252) {
        int q = t / 84, r = t - q * 84, p = r / 12, u = r - p * 12;
        if (pbase + p < NPTS) {
            int i0 = q * 57, i1 = (q == 2) ? 169 : i0 + 57;
            float tre = 0.f, tim = 0.f;
            for (int it = i0; it < i1; ++it) {
                float4 c = CTt[it * 12 + u];
                float2 gv = WeGV[p * 169 + it];
                tre += c.x * gv.x + c.y * gv.y;
                tim += c.z * gv.x + c.w * gv.y;
            }
            Tpar[p][u * 3 + q] = make_float2(tre, tim);
        }
    }
    __syncthreads();

    // ---- phase 6: layer-2 gerelu + trnorm + dense head
    if (t < NP && pbase + t < NPTS) {
        int p = t;
        float m = 0.f; float2 T[12]; float gg[12];
        #pragma unroll
        for (int u = 0; u < 12; ++u) {
            float2 A = Tpar[p][u * 3], B = Tpar[p][u * 3 + 1], C = Tpar[p][u * 3 + 2];
            float2 tt = make_float2(A.x + B.x + C.x, A.y + B.y + C.y);
            T[u] = tt;
            float g = tt.x > 0.f ? tt.x : 0.f;
            gg[u] = g;
            m += g * sqrtf(tt.x * tt.x + tt.y * tt.y);
        }
        float inv = 1.f / fmaxf(m * (1.f / 12.f), THRESH);
        float acc = db[0];
        #pragma unroll
        for (int u = 0; u < 12; ++u) {
            float s = gg[u] * inv * (1.f / 3.f);
            acc += s * (T[u].x * dw[2 * u] + T[u].y * dw[2 * u + 1]);
        }
        out[pbase + p] = acc;
    }
}

extern "C" void kernel_launch(void* const* d_in, const int* in_sizes, int n_in,
                              void* d_out, int out_size, void* d_ws, size_t ws_size,
                              hipStream_t stream) {
    const float* x  = (const float*)d_in[0];
    const float* w1 = (const float*)d_in[1];
    const float* w2 = (const float*)d_in[2];
    const float* dw = (const float*)d_in[3];
    const float* db = (const float*)d_in[4];
    float* outp = (float*)d_out;
    float4* CTt = (float4*)d_ws;          // 12*169*16 B = 32448 B

    geblnet_setup<<<(12 * 169 + 255) / 256, 256, 0, stream>>>(w2, CTt);

    const int nblocks = (NPTS + NP - 1) / NP;   // 1171
    geblnet_main<<<nblocks, 256, 0, stream>>>(
        (const float2*)x, (const float2*)w1, dw, db, CTt, outp);
}